// Round 2
// baseline (4281.499 us; speedup 1.0000x reference)
//
#include <hip/hip_runtime.h>
#include <stdint.h>

#define D_DIM 2048
#define K_DIM 64
#define T_DIM 2048
#define BT_DIM 16384   // B*T = 8*2048

// ---------------------------------------------------------------------------
// Kernel A: softmax over k of w[d,:], stored TRANSPOSED: pT[k,d].
// ---------------------------------------------------------------------------
__global__ __launch_bounds__(256) void softmax_k(const float* __restrict__ w,
                                                 float* __restrict__ pT) {
    const int lane = threadIdx.x & 63;
    const int d = blockIdx.x * 4 + (threadIdx.x >> 6);
    float v = w[d * K_DIM + lane];
    float m = v;
#pragma unroll
    for (int off = 32; off > 0; off >>= 1) m = fmaxf(m, __shfl_xor(m, off, 64));
    float e = expf(v - m);
    float s = e;
#pragma unroll
    for (int off = 32; off > 0; off >>= 1) s += __shfl_xor(s, off, 64);
    pT[(size_t)lane * D_DIM + d] = e / s;
}

// ---------------------------------------------------------------------------
// Kernel B: per-column min/max of w -> nT[k,d] = (w[d,k]-mn)/(mx-mn).
// ---------------------------------------------------------------------------
__global__ __launch_bounds__(256) void norm_k(const float* __restrict__ w,
                                              float* __restrict__ nT) {
    const int k = blockIdx.x;
    const int lane = threadIdx.x & 63;
    const int wave = threadIdx.x >> 6;
    float mn = 1e30f, mx = -1e30f;
    for (int d = threadIdx.x; d < D_DIM; d += 256) {
        float v = w[d * K_DIM + k];
        mn = fminf(mn, v);
        mx = fmaxf(mx, v);
    }
#pragma unroll
    for (int off = 32; off > 0; off >>= 1) {
        mn = fminf(mn, __shfl_xor(mn, off, 64));
        mx = fmaxf(mx, __shfl_xor(mx, off, 64));
    }
    __shared__ float red[8];
    if (lane == 0) { red[wave] = mn; red[4 + wave] = mx; }
    __syncthreads();
    mn = fminf(fminf(red[0], red[1]), fminf(red[2], red[3]));
    mx = fmaxf(fmaxf(red[4], red[5]), fmaxf(red[6], red[7]));
    const float inv = 1.0f / (mx - mn);
    for (int d = threadIdx.x; d < D_DIM; d += 256) {
        nT[k * D_DIM + d] = (w[d * K_DIM + k] - mn) * inv;
    }
}

// ---------------------------------------------------------------------------
// Kernel C1: scores = X @ P (fp32 VALU) -> per-row (argmax, sign).
// Block = 16 rows; 4 waves split D into quarters of 512; lane = k.
//
// v3: software-pipelined, zero inline asm.
//  - x tile reg-staged (global->VGPR->ds_write) into per-wave DOUBLE-buffered
//    LDS: tile it+1 loads issue at top of iteration it (~2000cy ahead), the
//    ds_write lands mid-iteration. Compiler tracks all deps in registers ->
//    counted vmcnt/lgkmcnt instead of a vmcnt(0) drain per step.
//  - pv (pT fragments, L2-hot) double-prefetched one compute-half ahead.
//  - No __syncthreads in the K-loop (per-wave private buffers).
//  - FMA chaining order identical to the 171us v1 -> stats bit-identical.
// ---------------------------------------------------------------------------
__global__ __launch_bounds__(256, 4) void gemm_stats_k(const float* __restrict__ x,
                                                       const float* __restrict__ pT,
                                                       int* __restrict__ stats) {
    const int lane = threadIdx.x & 63;
    const int wave = threadIdx.x >> 6;
    const int r0 = blockIdx.x * 16;
    const int dw0 = wave * (D_DIM / 4);            // this wave's d-quarter

    __shared__ float xs_all[4][2][16][64];         // 32 KB, per-wave double buffer
    float* buf0 = &xs_all[wave][0][0][0];
    float* buf1 = &xs_all[wave][1][0][0];

    float acc[16];
#pragma unroll
    for (int r = 0; r < 16; ++r) acc[r] = 0.0f;

    const float* __restrict__ xg = x + (size_t)r0 * D_DIM + dw0;    // wave's x panel
    const float* __restrict__ pg = pT + (size_t)lane * D_DIM + dw0; // lane = k row

    const int srow = lane >> 4;                    // 0..3 staging row in group
    const int scol = (lane & 15) * 4;              // 0,4,...,60 staging col

    // ---- prologue: stage tile 0, prefetch pv for it 0
    float4 xst[4];
#pragma unroll
    for (int j = 0; j < 4; ++j)
        xst[j] = *(const float4*)(xg + (size_t)(j * 4 + srow) * D_DIM + scol);
    float4 pv0[8], pv1[8];
#pragma unroll
    for (int j = 0; j < 8; ++j) pv0[j] = *(const float4*)(pg + j * 4);
#pragma unroll
    for (int j = 0; j < 8; ++j) pv1[j] = *(const float4*)(pg + 32 + j * 4);
#pragma unroll
    for (int j = 0; j < 4; ++j)
        *(float4*)(buf0 + (j * 4 + srow) * 64 + scol) = xst[j];

    float* cur = buf0;
    float* nxt = buf1;
    for (int it = 0; it < 8; ++it) {
        const int dn = (it + 1) * 64;
        // ---- issue next x tile loads (consumed by ds_write mid-iteration)
        if (it < 7) {
#pragma unroll
            for (int j = 0; j < 4; ++j)
                xst[j] = *(const float4*)(xg + (size_t)(j * 4 + srow) * D_DIM + dn + scol);
        }
        // ---- h0: 16 rows x 32 d from cur, pv0
#pragma unroll
        for (int r = 0; r < 16; ++r) {
            float a = acc[r];
#pragma unroll
            for (int j = 0; j < 8; ++j) {
                const float4 xv = *(const float4*)(cur + r * 64 + j * 4);
                a = fmaf(xv.x, pv0[j].x, a);
                a = fmaf(xv.y, pv0[j].y, a);
                a = fmaf(xv.z, pv0[j].z, a);
                a = fmaf(xv.w, pv0[j].w, a);
            }
            acc[r] = a;
        }
        // ---- prefetch pv0(it+1); write next x tile to alternate buffer
        if (it < 7) {
#pragma unroll
            for (int j = 0; j < 8; ++j) pv0[j] = *(const float4*)(pg + dn + j * 4);
#pragma unroll
            for (int j = 0; j < 4; ++j)
                *(float4*)(nxt + (j * 4 + srow) * 64 + scol) = xst[j];
        }
        // ---- h1: 16 rows x 32 d from cur, pv1
#pragma unroll
        for (int r = 0; r < 16; ++r) {
            float a = acc[r];
#pragma unroll
            for (int j = 0; j < 8; ++j) {
                const float4 xv = *(const float4*)(cur + r * 64 + 32 + j * 4);
                a = fmaf(xv.x, pv1[j].x, a);
                a = fmaf(xv.y, pv1[j].y, a);
                a = fmaf(xv.z, pv1[j].z, a);
                a = fmaf(xv.w, pv1[j].w, a);
            }
            acc[r] = a;
        }
        // ---- prefetch pv1(it+1)
        if (it < 7) {
#pragma unroll
            for (int j = 0; j < 8; ++j) pv1[j] = *(const float4*)(pg + dn + 32 + j * 4);
        }
        float* t = cur; cur = nxt; nxt = t;
    }

    // ---- cross-wave reduction + 64-lane argmax (first-index tie-break)
    // red overlays the staging buffers (16 KB of the 32 KB) after a barrier.
    __syncthreads();
    float (*red)[16][64] = reinterpret_cast<float (*)[16][64]>(&xs_all[0][0][0][0]);
#pragma unroll
    for (int r = 0; r < 16; ++r) red[wave][r][lane] = acc[r];
    __syncthreads();

#pragma unroll
    for (int rr = 0; rr < 4; ++rr) {
        const int r = wave * 4 + rr;
        float v = red[0][r][lane] + red[1][r][lane] + red[2][r][lane] + red[3][r][lane];
        int idx = lane;
#pragma unroll
        for (int off = 32; off > 0; off >>= 1) {
            const float ov = __shfl_xor(v, off, 64);
            const int oi = __shfl_xor(idx, off, 64);
            if (ov > v || (ov == v && oi < idx)) { v = ov; idx = oi; }
        }
        if (lane == 0) stats[r0 + r] = idx | ((v < 0.0f) ? (1 << 8) : 0);
    }
}

// ---------------------------------------------------------------------------
// Kernel C2: out[r,d] = x[r,d] * (1 + W), W from stats[r-1]; rows t==0: W=0.
// v2: 8 rows per block (grid 16384 -> 2048) to amortize dispatch overhead.
// ---------------------------------------------------------------------------
__global__ __launch_bounds__(256) void output_k(const float* __restrict__ x,
                                                const float* __restrict__ nT,
                                                const int* __restrict__ stats,
                                                float* __restrict__ out) {
    const int tid = threadIdx.x;
#pragma unroll 1
    for (int rr = 0; rr < 8; ++rr) {
        const int row = blockIdx.x * 8 + rr;
        const int t = row & (T_DIM - 1);
        const float4* x4 = (const float4*)(x + (size_t)row * D_DIM);
        float4* o4 = (float4*)(out + (size_t)row * D_DIM);
        if (t == 0) {
#pragma unroll
            for (int it = 0; it < 2; ++it) {
                const int i = tid + it * 256;
                o4[i] = x4[i];
            }
            continue;
        }
        const int s = stats[row - 1];
        const int ind = s & 0xff;
        const bool neg = (s >> 8) & 1;
        const float4* n4 = (const float4*)(nT + (size_t)ind * D_DIM);
#pragma unroll
        for (int it = 0; it < 2; ++it) {
            const int i = tid + it * 256;
            const float4 xv = x4[i];
            const float4 nv = n4[i];
            float4 r;
            const float w0 = neg ? 1.0f - nv.x : nv.x;
            const float w1 = neg ? 1.0f - nv.y : nv.y;
            const float w2 = neg ? 1.0f - nv.z : nv.z;
            const float w3 = neg ? 1.0f - nv.w : nv.w;
            r.x = fmaf(xv.x, w0, xv.x);
            r.y = fmaf(xv.y, w1, xv.y);
            r.z = fmaf(xv.z, w2, xv.z);
            r.w = fmaf(xv.w, w3, xv.w);
            o4[i] = r;
        }
    }
}

extern "C" void kernel_launch(void* const* d_in, const int* in_sizes, int n_in,
                              void* d_out, int out_size, void* d_ws, size_t ws_size,
                              hipStream_t stream) {
    const float* x = (const float*)d_in[0];   // [B,T,D] fp32
    const float* w = (const float*)d_in[1];   // [D,K] fp32
    float* out = (float*)d_out;

    float* pT = (float*)d_ws;                 // [K,D]  512 KB (transposed softmax)
    float* nT = pT + (size_t)K_DIM * D_DIM;   // [K,D]  512 KB
    int* stats = (int*)(nT + (size_t)K_DIM * D_DIM);  // [B*T] 64 KB

    softmax_k<<<D_DIM / 4, 256, 0, stream>>>(w, pT);
    norm_k<<<K_DIM, 256, 0, stream>>>(w, nT);
    gemm_stats_k<<<BT_DIM / 16, 256, 0, stream>>>(x, pT, stats);
    output_k<<<BT_DIM / 8, 256, 0, stream>>>(x, nT, stats, out);
}

// Round 3
// 314.170 us; speedup vs baseline: 13.6280x; 13.6280x over previous
//
#include <hip/hip_runtime.h>
#include <stdint.h>

#define D_DIM 2048
#define K_DIM 64
#define T_DIM 2048
#define BT_DIM 16384   // B*T = 8*2048

typedef __attribute__((address_space(3))) uint32_t lds_u32;
typedef const __attribute__((address_space(1))) uint32_t glob_u32;

// ---------------------------------------------------------------------------
// Kernel A: softmax over k of w[d,:], stored PACKED for the gemm:
//   pC[(d>>2)*256 + k*4 + (d&3)] = softmax(w[d,:])[k]
// Layout groups 4 d-values per k so a gemm lane loads its 4 k rows' 4-d
// fragments as 4 consecutive float4 (64 B/lane, 16 lanes = 1 KB coalesced).
// ---------------------------------------------------------------------------
__global__ __launch_bounds__(256) void softmax_k(const float* __restrict__ w,
                                                 float* __restrict__ pC) {
    const int lane = threadIdx.x & 63;
    const int d = blockIdx.x * 4 + (threadIdx.x >> 6);
    float v = w[d * K_DIM + lane];
    float m = v;
#pragma unroll
    for (int off = 32; off > 0; off >>= 1) m = fmaxf(m, __shfl_xor(m, off, 64));
    float e = expf(v - m);
    float s = e;
#pragma unroll
    for (int off = 32; off > 0; off >>= 1) s += __shfl_xor(s, off, 64);
    pC[(d >> 2) * 256 + lane * 4 + (d & 3)] = e / s;
}

// ---------------------------------------------------------------------------
// Kernel B: per-column min/max of w -> nT[k,d] = (w[d,k]-mn)/(mx-mn).
// ---------------------------------------------------------------------------
__global__ __launch_bounds__(256) void norm_k(const float* __restrict__ w,
                                              float* __restrict__ nT) {
    const int k = blockIdx.x;
    const int lane = threadIdx.x & 63;
    const int wave = threadIdx.x >> 6;
    float mn = 1e30f, mx = -1e30f;
    for (int d = threadIdx.x; d < D_DIM; d += 256) {
        float v = w[d * K_DIM + k];
        mn = fminf(mn, v);
        mx = fmaxf(mx, v);
    }
#pragma unroll
    for (int off = 32; off > 0; off >>= 1) {
        mn = fminf(mn, __shfl_xor(mn, off, 64));
        mx = fmaxf(mx, __shfl_xor(mx, off, 64));
    }
    __shared__ float red[8];
    if (lane == 0) { red[wave] = mn; red[4 + wave] = mx; }
    __syncthreads();
    mn = fminf(fminf(red[0], red[1]), fminf(red[2], red[3]));
    mx = fmaxf(fmaxf(red[4], red[5]), fmaxf(red[6], red[7]));
    const float inv = 1.0f / (mx - mn);
    for (int d = threadIdx.x; d < D_DIM; d += 256) {
        nT[k * D_DIM + d] = (w[d * K_DIM + k] - mn) * inv;
    }
}

// ---------------------------------------------------------------------------
// Kernel C1: scores = X @ P (fp32 VALU) -> per-row (argmax, sign).
// v4: register-tiled. Block = 32 rows, 4 waves = d-quarters (512 d each).
// Lane = (rg = lane>>4 owning 8 rows) x (kg = lane&15 owning k = kg*4..+3).
// acc[8][4] per lane. LDS x-broadcast traffic drops 4x vs lane-per-k
// (16B ds_read feeds 16 FMAs instead of 4); p comes from L2 via packed pC.
// x tile [32 r][64 d] staged with global_load_lds, XOR-swizzled (source
// pre-swizzle + read-side XOR, rule: both-sides-or-neither) so the 4
// row-groups' broadcast reads hit 4 distinct bank quads (was 4-way conflict).
// Accumulation order per (r,k) is ascending d over the wave's quarter, and
// the cross-wave reduce + argmax are byte-identical to the 171us kernel ->
// stats bit-identical.
// ---------------------------------------------------------------------------
__global__ __launch_bounds__(256, 2) void gemm_stats_k(const float* __restrict__ x,
                                                       const float* __restrict__ pC,
                                                       int* __restrict__ stats) {
    const int lane = threadIdx.x & 63;
    const int wave = threadIdx.x >> 6;
    const int r0 = blockIdx.x * 32;
    const int dw0 = wave * (D_DIM / 4);            // this wave's d-quarter
    const int rg = lane >> 4;                      // 0..3: rows rg*8..rg*8+7
    const int kg = lane & 15;                      // k = kg*4 + kk

    __shared__ float xs_all[4][32 * 64];           // 32 KB, per-wave x tile
    float* xs = xs_all[wave];

    float acc[8][4];
#pragma unroll
    for (int rr = 0; rr < 8; ++rr)
#pragma unroll
        for (int kk = 0; kk < 4; ++kk) acc[rr][kk] = 0.0f;

    const float* __restrict__ xg = x + (size_t)r0 * D_DIM + dw0;   // wave x panel
    // packed p: this wave's quarter starts at chunk wave*128; lane's 4 k rows
    const float* __restrict__ pgBase = pC + (size_t)(wave * 128) * 256 + kg * 16;

    const int srow = lane >> 4;                    // staging row within group of 4

#pragma unroll 1
    for (int it = 0; it < 8; ++it) {
        // ---- stage x tile [32 r][64 d]: 8 x global_load_lds (1 KB each).
        // LDS dest is linear; global source column is XOR-pre-swizzled so the
        // read-side XOR (slot = c ^ rg) sees the right data.
#pragma unroll
        for (int j = 0; j < 8; ++j) {
            const int swz = (j >> 1) & 3;          // = (row>>3)&3 for this instr
            const float* src = xg + (size_t)(j * 4 + srow) * D_DIM + it * 64
                               + ((kg ^ swz) << 2);
            __builtin_amdgcn_global_load_lds((glob_u32*)src,
                                             (lds_u32*)(xs + j * 256),
                                             16, 0, 0);
        }
        asm volatile("s_waitcnt vmcnt(0)" ::: "memory");

        // ---- compute: 16 sub-chunks of 4 d
#pragma unroll
        for (int c = 0; c < 16; ++c) {
            const float* pcc = pgBase + (size_t)(it * 16 + c) * 256;
            float4 pv[4];
#pragma unroll
            for (int kk = 0; kk < 4; ++kk)
                pv[kk] = *(const float4*)(pcc + kk * 4);
#pragma unroll
            for (int rr = 0; rr < 8; ++rr) {
                const int row = rg * 8 + rr;
                const float4 xv = *(const float4*)(xs + row * 64 + ((c ^ rg) << 2));
#pragma unroll
                for (int kk = 0; kk < 4; ++kk) {
                    float a = acc[rr][kk];
                    a = fmaf(xv.x, pv[kk].x, a);
                    a = fmaf(xv.y, pv[kk].y, a);
                    a = fmaf(xv.z, pv[kk].z, a);
                    a = fmaf(xv.w, pv[kk].w, a);
                    acc[rr][kk] = a;
                }
            }
        }
    }

    // ---- cross-wave reduction + 64-lane argmax (identical to v1) ----------
    __syncthreads();                               // all waves done with xs
    float (*red)[32][64] = reinterpret_cast<float (*)[32][64]>(&xs_all[0][0]);
#pragma unroll
    for (int rr = 0; rr < 8; ++rr)
#pragma unroll
        for (int kk = 0; kk < 4; ++kk)
            red[wave][rg * 8 + rr][kg * 4 + kk] = acc[rr][kk];
    __syncthreads();

#pragma unroll
    for (int rr = 0; rr < 8; ++rr) {
        const int r = wave * 8 + rr;
        float v = red[0][r][lane] + red[1][r][lane] + red[2][r][lane] + red[3][r][lane];
        int idx = lane;
#pragma unroll
        for (int off = 32; off > 0; off >>= 1) {
            const float ov = __shfl_xor(v, off, 64);
            const int oi = __shfl_xor(idx, off, 64);
            if (ov > v || (ov == v && oi < idx)) { v = ov; idx = oi; }
        }
        if (lane == 0) stats[r0 + r] = idx | ((v < 0.0f) ? (1 << 8) : 0);
    }
}

// ---------------------------------------------------------------------------
// Kernel C2: out[r,d] = x[r,d] * (1 + W), W from stats[r-1]; rows t==0: W=0.
// 8 rows per block (grid 2048) to amortize dispatch overhead.
// ---------------------------------------------------------------------------
__global__ __launch_bounds__(256) void output_k(const float* __restrict__ x,
                                                const float* __restrict__ nT,
                                                const int* __restrict__ stats,
                                                float* __restrict__ out) {
    const int tid = threadIdx.x;
#pragma unroll 1
    for (int rr = 0; rr < 8; ++rr) {
        const int row = blockIdx.x * 8 + rr;
        const int t = row & (T_DIM - 1);
        const float4* x4 = (const float4*)(x + (size_t)row * D_DIM);
        float4* o4 = (float4*)(out + (size_t)row * D_DIM);
        if (t == 0) {
#pragma unroll
            for (int it = 0; it < 2; ++it) {
                const int i = tid + it * 256;
                o4[i] = x4[i];
            }
            continue;
        }
        const int s = stats[row - 1];
        const int ind = s & 0xff;
        const bool neg = (s >> 8) & 1;
        const float4* n4 = (const float4*)(nT + (size_t)ind * D_DIM);
#pragma unroll
        for (int it = 0; it < 2; ++it) {
            const int i = tid + it * 256;
            const float4 xv = x4[i];
            const float4 nv = n4[i];
            float4 r;
            const float w0 = neg ? 1.0f - nv.x : nv.x;
            const float w1 = neg ? 1.0f - nv.y : nv.y;
            const float w2 = neg ? 1.0f - nv.z : nv.z;
            const float w3 = neg ? 1.0f - nv.w : nv.w;
            r.x = fmaf(xv.x, w0, xv.x);
            r.y = fmaf(xv.y, w1, xv.y);
            r.z = fmaf(xv.z, w2, xv.z);
            r.w = fmaf(xv.w, w3, xv.w);
            o4[i] = r;
        }
    }
}

extern "C" void kernel_launch(void* const* d_in, const int* in_sizes, int n_in,
                              void* d_out, int out_size, void* d_ws, size_t ws_size,
                              hipStream_t stream) {
    const float* x = (const float*)d_in[0];   // [B,T,D] fp32
    const float* w = (const float*)d_in[1];   // [D,K] fp32
    float* out = (float*)d_out;

    float* pC = (float*)d_ws;                 // [D/4][K][4] packed softmax, 512 KB
    float* nT = pC + (size_t)K_DIM * D_DIM;   // [K,D]  512 KB
    int* stats = (int*)(nT + (size_t)K_DIM * D_DIM);  // [B*T] 64 KB

    softmax_k<<<D_DIM / 4, 256, 0, stream>>>(w, pC);
    norm_k<<<K_DIM, 256, 0, stream>>>(w, nT);
    gemm_stats_k<<<BT_DIM / 32, 256, 0, stream>>>(x, pC, stats);
    output_k<<<BT_DIM / 8, 256, 0, stream>>>(x, nT, stats, out);
}